// Round 9
// baseline (99.118 us; speedup 1.0000x reference)
//
#include <hip/hip_runtime.h>
#include <math.h>

#define S 4096
#define EPS 1e-5f

#if __has_builtin(__builtin_amdgcn_exp2f)
#define EXP2F(x) __builtin_amdgcn_exp2f(x)
#else
#define EXP2F(x) exp2f(x)
#endif

// Full-rate (VALU-pipe) exp2: range-reduce + deg-3 minimax + ldexp.
// Rel err ~3e-5 on [-0.5,0.5] — far below the f16 pack rounding (~5e-4).
static __device__ __forceinline__ float exp2_poly(float x) {
    float nf = __builtin_rintf(x);            // v_rndne_f32
    float f  = x - nf;                        // v_sub_f32
    float p  = fmaf(fmaf(fmaf(0.0558263180f, f, 0.240153617f),
                         f, 0.693153073f), f, 0.999999925f);  // 3x v_fma_f32
    return ldexpf(p, (int)nf);                // v_cvt_i32_f32 + v_ldexp_f32
}

// ws float-index offsets
#define WS_PSUM 0            // [64]
#define WS_PSQ  64           // [64]
#define WS_ATT  16384        // [64*4096] f32
// ws byte offsets for f16 regions (each 512 KB)
#define QT_B 1310720
#define KT_B 1835008
#define VB_B 2359296

typedef _Float16 h8_t __attribute__((ext_vector_type(8)));
typedef __fp16   fp16v2 __attribute__((ext_vector_type(2)));
typedef float    f4_t  __attribute__((ext_vector_type(4)));
typedef float    f16_t __attribute__((ext_vector_type(16)));

union H8 { h8_t h; int4 v; int i[4]; };

static __device__ __forceinline__ int pkrtz(float a, float b) {
    fp16v2 p = __builtin_amdgcn_cvt_pkrtz(a, b);
    union { fp16v2 h; int i; } u; u.h = p; return u.i;
}

// ---------------- GroupNorm stage 1: per-channel partial sums ----------------
__global__ __launch_bounds__(256) void k_gnstat1(const float* __restrict__ x,
                                                 float* __restrict__ ws) {
    int b = blockIdx.x;
    int tid = threadIdx.x;
    const float4* p = (const float4*)(x + b * 4096);
    float s = 0.f, sq = 0.f;
    #pragma unroll
    for (int i = 0; i < 4; ++i) {
        float4 v = p[tid + i * 256];
        s  += v.x + v.y + v.z + v.w;
        sq += v.x * v.x + v.y * v.y + v.z * v.z + v.w * v.w;
    }
    #pragma unroll
    for (int m = 32; m >= 1; m >>= 1) {
        s  += __shfl_xor(s, m);
        sq += __shfl_xor(sq, m);
    }
    __shared__ float ls[4], lq[4];
    int w = tid >> 6;
    if ((tid & 63) == 0) { ls[w] = s; lq[w] = sq; }
    __syncthreads();
    if (tid == 0) {
        ws[WS_PSUM + b] = ls[0] + ls[1] + ls[2] + ls[3];
        ws[WS_PSQ  + b] = lq[0] + lq[1] + lq[2] + lq[3];
    }
}

// ---------------- QKV projection (GN fold fused), writes f16 MFMA layouts ----------------
// grid (16, 48), block 256: s-tile 256 (1 s/thread), o-tile 4 (half head-slice)
__global__ __launch_bounds__(256) void k_qkv(const float* __restrict__ x,
                                             const float* __restrict__ qkvw,
                                             const float* __restrict__ gnw,
                                             const float* __restrict__ gnb,
                                             float* __restrict__ ws) {
    __shared__ float la[64], lb2[64], lw[256], lbias[4];
    int tid = threadIdx.x;
    int o0 = blockIdx.y * 4;
    int s = blockIdx.x * 256 + tid;

    if (tid < 64) {                 // finalize GN stats (redundant per block, cheap)
        float sm = ws[WS_PSUM + tid];
        float sq = ws[WS_PSQ + tid];
        #pragma unroll
        for (int m = 1; m < 8; m <<= 1) {
            sm += __shfl_xor(sm, m);
            sq += __shfl_xor(sq, m);
        }
        const float inv_n = 1.0f / 32768.0f;
        float mu  = sm * inv_n;
        float var = sq * inv_n - mu * mu;
        float rs  = rsqrtf(var + EPS);
        float a   = rs * gnw[tid];
        la[tid]  = a;
        lb2[tid] = gnb[tid] - mu * a;
    }
    __syncthreads();
    lw[tid] = qkvw[o0 * 64 + tid] * la[tid & 63];
    {
        int wv = tid >> 6, ln = tid & 63;   // wave wv handles o = o0+wv
        float pb = qkvw[(o0 + wv) * 64 + ln] * lb2[ln];
        #pragma unroll
        for (int m = 1; m < 64; m <<= 1) pb += __shfl_xor(pb, m);
        if (ln == 0) lbias[wv] = pb;
    }
    __syncthreads();

    float acc[4];
    #pragma unroll
    for (int o = 0; o < 4; ++o) acc[o] = lbias[o];
    for (int c = 0; c < 64; ++c) {
        float xv = x[c * S + s];
        #pragma unroll
        for (int o = 0; o < 4; ++o) acc[o] = fmaf(lw[o * 64 + c], xv, acc[o]);
    }

    char* base = (char*)ws;
    if (o0 < 64) {                       // Q -> Qt[h][s][d], pre-scaled by 8^-0.5*log2(e)
        const float qsc = 0.51006776f;
        int hh = o0 >> 3, db = o0 & 7;   // db in {0,4}
        int2 r;
        r.x = pkrtz(acc[0] * qsc, acc[1] * qsc);
        r.y = pkrtz(acc[2] * qsc, acc[3] * qsc);
        *(int2*)(base + QT_B + (size_t)(hh * 4096 + s) * 16 + db * 2) = r;
    } else if (o0 < 128) {               // K -> Kt[h][t][d]
        int hh = (o0 - 64) >> 3, db = o0 & 7;
        int2 r;
        r.x = pkrtz(acc[0], acc[1]);
        r.y = pkrtz(acc[2], acc[3]);
        *(int2*)(base + KT_B + (size_t)(hh * 4096 + s) * 16 + db * 2) = r;
    } else {                             // V -> Vb[h][d][t]
        int hh = (o0 - 128) >> 3, db = o0 & 7;
        _Float16* vb = (_Float16*)(base + VB_B);
        #pragma unroll
        for (int d = 0; d < 4; ++d)
            vb[(size_t)((hh * 8 + db + d) * 4096) + s] = (_Float16)acc[d];
    }
}

// ---------------- Attention via f16 MFMA (R7 body + hybrid-pipe exp) --------
// grid (128, 8), block 512: 32 queries/block, 8 waves = 8 t-chunks of 512.
// QK: ONE 32x32x16 MFMA; softmax exp SPLIT ACROSS PIPES: half the scores via
// v_exp_f32 (trans unit), half via full-rate VALU polynomial — the trans unit
// (1/4..1/16 rate) is the suspected saturated pipe that pinned k_attn at
// ~22us across R5-R8 structural variants. P^T via per-wave LDS tile; PV: 2x
// 16x16x32 with (V|ones) A-frag so acc row d=8 = softmax denominator.
__global__ __launch_bounds__(512, 6) void k_attn(float* __restrict__ ws) {
    const int h = blockIdx.y;
    const int q0 = blockIdx.x * 32;
    const int tid = threadIdx.x;
    const int w = tid >> 6;          // 0..7 t-chunk
    const int lane = tid & 63;
    const int col16 = lane & 15;
    const int quad = lane >> 4;
    const int col32 = lane & 31;
    const int half = lane >> 5;

    const char* base = (const char*)ws;
    const _Float16* Qt = (const _Float16*)(base + QT_B) + (size_t)h * 4096 * 8;
    const _Float16* Kt = (const _Float16*)(base + KT_B) + (size_t)h * 4096 * 8;
    const _Float16* Vb = (const _Float16*)(base + VB_B) + (size_t)h * 8 * 4096;

    __shared__ _Float16 Plds[8][32][40];   // per-wave 32s x 32t tile, +8 pad
    __shared__ f4_t red[7][2][64];

    // Q B-frag (32x32x16): lane<32 holds Q[s=col32][d=0..7]; upper half zero
    H8 qf;
    qf.i[0] = qf.i[1] = qf.i[2] = qf.i[3] = 0;
    if (half == 0) qf.v = *(const int4*)(Qt + (size_t)(q0 + col32) * 8);

    // K A-frag: lane<32 holds K[t=col32][d=0..7]; upper half stays zero
    H8 kf;
    kf.i[0] = kf.i[1] = kf.i[2] = kf.i[3] = 0;
    // V A-frag (16x16x32): rows m=d: d<8 data (loaded per iter), d==8 ones, else 0
    H8 vf;
    {
        int c8 = (col16 == 8) ? 0x3C003C00 : 0;
        vf.i[0] = c8; vf.i[1] = c8; vf.i[2] = c8; vf.i[3] = c8;
    }

    const int tbase = w * 512;
    if (half == 0) kf.v = *(const int4*)(Kt + (size_t)(tbase + col32) * 8);

    f4_t acc0 = {0.f, 0.f, 0.f, 0.f};
    f4_t acc1 = {0.f, 0.f, 0.f, 0.f};
    f16_t zc = {0.f, 0.f, 0.f, 0.f, 0.f, 0.f, 0.f, 0.f,
                0.f, 0.f, 0.f, 0.f, 0.f, 0.f, 0.f, 0.f};
    _Float16* Pw = &Plds[w][0][0];

    for (int it = 0; it < 16; ++it) {
        const int tt = tbase + it * 32;
        // V for THIS iter: consumer (PV) is after exp+LDS round-trip -> slack
        if (col16 < 8)
            vf.v = *(const int4*)(Vb + (size_t)col16 * 4096 + tt + quad * 8);

        f16_t sc = __builtin_amdgcn_mfma_f32_32x32x16_f16(kf.h, qf.h, zc, 0, 0, 0);

        // prefetch next K tile (reads past-end junk at it=15 stay inside ws)
        H8 nk = kf;                      // keeps upper-half zeros
        if (half == 0)
            nk.v = *(const int4*)(Kt + (size_t)(tt + 32 + col32) * 8);

        // Hybrid exp: per 4-group, 2 on the trans unit + 2 on the VALU pipe
        // (independent ops -> the wave co-issues; both pipes run in parallel)
        #pragma unroll
        for (int b = 0; b < 4; ++b) {
            float e0 = EXP2F(sc[4 * b]);
            float e2 = exp2_poly(sc[4 * b + 2]);
            float e1 = EXP2F(sc[4 * b + 1]);
            float e3 = exp2_poly(sc[4 * b + 3]);
            int2 wv = { pkrtz(e0, e1), pkrtz(e2, e3) };
            *(int2*)(Pw + col32 * 40 + 8 * b + 4 * half) = wv;
        }

        // B-frag reads: lane(quad,col16) takes P[s][t=quad*8..+7]
        H8 p0, p1;
        p0.v = *(const int4*)(Pw + col16 * 40 + quad * 8);
        p1.v = *(const int4*)(Pw + (col16 + 16) * 40 + quad * 8);

        acc0 = __builtin_amdgcn_mfma_f32_16x16x32_f16(vf.h, p0.h, acc0, 0, 0, 0);
        acc1 = __builtin_amdgcn_mfma_f32_16x16x32_f16(vf.h, p1.h, acc1, 0, 0, 0);

        kf = nk;
    }

    if (w > 0) { red[w - 1][0][lane] = acc0; red[w - 1][1][lane] = acc1; }
    __syncthreads();
    if (w == 0) {
        #pragma unroll
        for (int r = 0; r < 7; ++r) {
            acc0 += red[r][0][lane];
            acc1 += red[r][1][lane];
        }
        float inv0 = 1.0f / __shfl(acc0[0], 32 + col16, 64);  // row d=8 = denom
        float inv1 = 1.0f / __shfl(acc1[0], 32 + col16, 64);
        if (quad < 2) {
            float* att = ws + WS_ATT + (size_t)(h * 8 + quad * 4) * S + q0;
            #pragma unroll
            for (int r = 0; r < 4; ++r) {
                att[r * S + col16]      = acc0[r] * inv0;
                att[r * S + 16 + col16] = acc1[r] * inv1;
            }
        }
    }
}

// ---------------- Out projection + bias + residual ----------------
// grid (16, 64), block 256: s-tile 256 (1 s/thread), o-tile 1 -> 1024 blocks
__global__ __launch_bounds__(256) void k_out(const float* __restrict__ x,
                                             const float* __restrict__ outw,
                                             const float* __restrict__ outb,
                                             const float* __restrict__ ws,
                                             float* __restrict__ out) {
    __shared__ float lw[64];
    int tid = threadIdx.x;
    int o = blockIdx.y;
    int s = blockIdx.x * 256 + tid;
    if (tid < 64) lw[tid] = outw[o * 64 + tid];
    __syncthreads();

    float acc = outb[o];
    const float* att = ws + WS_ATT;
    for (int c = 0; c < 64; ++c)
        acc = fmaf(lw[c], att[c * S + s], acc);
    out[o * S + s] = acc + x[o * S + s];
}

extern "C" void kernel_launch(void* const* d_in, const int* in_sizes, int n_in,
                              void* d_out, int out_size, void* d_ws, size_t ws_size,
                              hipStream_t stream) {
    const float* x    = (const float*)d_in[0];
    const float* gnw  = (const float*)d_in[1];
    const float* gnb  = (const float*)d_in[2];
    const float* qkvw = (const float*)d_in[3];
    const float* outw = (const float*)d_in[4];
    const float* outb = (const float*)d_in[5];
    float* out = (float*)d_out;
    float* ws  = (float*)d_ws;

    hipLaunchKernelGGL(k_gnstat1, dim3(64), dim3(256), 0, stream, x, ws);
    hipLaunchKernelGGL(k_qkv, dim3(16, 48), dim3(256), 0, stream, x, qkvw, gnw, gnb, ws);
    hipLaunchKernelGGL(k_attn, dim3(128, 8), dim3(512), 0, stream, ws);
    hipLaunchKernelGGL(k_out, dim3(16, 64), dim3(256), 0, stream, x, outw, outb, ws, out);
}

// Round 10
// 93.025 us; speedup vs baseline: 1.0655x; 1.0655x over previous
//
#include <hip/hip_runtime.h>
#include <math.h>

#define S 4096
#define EPS 1e-5f

// ws float-index offsets
#define WS_PSUM 0            // [64]
#define WS_PSQ  64           // [64]
#define WS_ATT  16384        // [64*4096] f32
// ws byte offsets for f16 regions (each 512 KB)
#define QT_B 1310720
#define KT_B 1835008
#define VB_B 2359296

typedef _Float16 h8_t __attribute__((ext_vector_type(8)));
typedef __fp16   fp16v2 __attribute__((ext_vector_type(2)));
typedef float    f4_t  __attribute__((ext_vector_type(4)));
typedef float    f16_t __attribute__((ext_vector_type(16)));

union H8 { h8_t h; int4 v; int i[4]; };

static __device__ __forceinline__ int pkrtz(float a, float b) {
    fp16v2 p = __builtin_amdgcn_cvt_pkrtz(a, b);
    union { fp16v2 h; int i; } u; u.h = p; return u.i;
}

// Schraudolph: f16 bits of ~2^x = (int)(1024*x + 15360 - 44).
// fma + cvt (2 full-rate VALU ops) vs v_exp_f32 (8-cyc trans) + pack.
// Ripple +-3% (centered by the -44); scores |x|<~9 -> bits in [6.3k,24.3k], safe.
#define EXP2_BITS(x) ((int)fmaf((x), 1024.0f, 15316.0f))

// ---------------- GroupNorm stage 1: per-channel partial sums ----------------
__global__ __launch_bounds__(256) void k_gnstat1(const float* __restrict__ x,
                                                 float* __restrict__ ws) {
    int b = blockIdx.x;
    int tid = threadIdx.x;
    const float4* p = (const float4*)(x + b * 4096);
    float s = 0.f, sq = 0.f;
    #pragma unroll
    for (int i = 0; i < 4; ++i) {
        float4 v = p[tid + i * 256];
        s  += v.x + v.y + v.z + v.w;
        sq += v.x * v.x + v.y * v.y + v.z * v.z + v.w * v.w;
    }
    #pragma unroll
    for (int m = 32; m >= 1; m >>= 1) {
        s  += __shfl_xor(s, m);
        sq += __shfl_xor(sq, m);
    }
    __shared__ float ls[4], lq[4];
    int w = tid >> 6;
    if ((tid & 63) == 0) { ls[w] = s; lq[w] = sq; }
    __syncthreads();
    if (tid == 0) {
        ws[WS_PSUM + b] = ls[0] + ls[1] + ls[2] + ls[3];
        ws[WS_PSQ  + b] = lq[0] + lq[1] + lq[2] + lq[3];
    }
}

// ---------------- QKV projection (GN fold fused), writes f16 MFMA layouts ----------------
// grid (16, 48), block 256: s-tile 256 (1 s/thread), o-tile 4 (half head-slice)
__global__ __launch_bounds__(256) void k_qkv(const float* __restrict__ x,
                                             const float* __restrict__ qkvw,
                                             const float* __restrict__ gnw,
                                             const float* __restrict__ gnb,
                                             float* __restrict__ ws) {
    __shared__ float la[64], lb2[64], lw[256], lbias[4];
    int tid = threadIdx.x;
    int o0 = blockIdx.y * 4;
    int s = blockIdx.x * 256 + tid;

    if (tid < 64) {                 // finalize GN stats (redundant per block, cheap)
        float sm = ws[WS_PSUM + tid];
        float sq = ws[WS_PSQ + tid];
        #pragma unroll
        for (int m = 1; m < 8; m <<= 1) {
            sm += __shfl_xor(sm, m);
            sq += __shfl_xor(sq, m);
        }
        const float inv_n = 1.0f / 32768.0f;
        float mu  = sm * inv_n;
        float var = sq * inv_n - mu * mu;
        float rs  = rsqrtf(var + EPS);
        float a   = rs * gnw[tid];
        la[tid]  = a;
        lb2[tid] = gnb[tid] - mu * a;
    }
    __syncthreads();
    lw[tid] = qkvw[o0 * 64 + tid] * la[tid & 63];
    {
        int wv = tid >> 6, ln = tid & 63;   // wave wv handles o = o0+wv
        float pb = qkvw[(o0 + wv) * 64 + ln] * lb2[ln];
        #pragma unroll
        for (int m = 1; m < 64; m <<= 1) pb += __shfl_xor(pb, m);
        if (ln == 0) lbias[wv] = pb;
    }
    __syncthreads();

    float acc[4];
    #pragma unroll
    for (int o = 0; o < 4; ++o) acc[o] = lbias[o];
    for (int c = 0; c < 64; ++c) {
        float xv = x[c * S + s];
        #pragma unroll
        for (int o = 0; o < 4; ++o) acc[o] = fmaf(lw[o * 64 + c], xv, acc[o]);
    }

    char* base = (char*)ws;
    if (o0 < 64) {                       // Q -> Qt[h][s][d], pre-scaled by 8^-0.5*log2(e)
        const float qsc = 0.51006776f;
        int hh = o0 >> 3, db = o0 & 7;   // db in {0,4}
        int2 r;
        r.x = pkrtz(acc[0] * qsc, acc[1] * qsc);
        r.y = pkrtz(acc[2] * qsc, acc[3] * qsc);
        *(int2*)(base + QT_B + (size_t)(hh * 4096 + s) * 16 + db * 2) = r;
    } else if (o0 < 128) {               // K -> Kt[h][t][d]
        int hh = (o0 - 64) >> 3, db = o0 & 7;
        int2 r;
        r.x = pkrtz(acc[0], acc[1]);
        r.y = pkrtz(acc[2], acc[3]);
        *(int2*)(base + KT_B + (size_t)(hh * 4096 + s) * 16 + db * 2) = r;
    } else {                             // V -> Vb[h][d][t]
        int hh = (o0 - 128) >> 3, db = o0 & 7;
        _Float16* vb = (_Float16*)(base + VB_B);
        #pragma unroll
        for (int d = 0; d < 4; ++d)
            vb[(size_t)((hh * 8 + db + d) * 4096) + s] = (_Float16)acc[d];
    }
}

// ---------------- Attention via f16 MFMA (R8 body + Schraudolph exp) --------
// grid (128, 8), block 512: 32 queries/block, 8 waves = 8 t-chunks of 512.
// QK: ONE 32x32x16 MFMA; softmax exp via the f16-bits trick (fma+cvt, full
// rate VALU) — R9 proved the kernel is VALU-ISSUE bound with v_exp_f32 at
// ~8cyc issue-blocking; only a <=2-op/score replacement wins. pkrtz is gone
// (bits ARE the f16 pair). P^T via per-wave LDS tile; PV: 2x 16x16x32 with
// (V|ones) A-frag so acc row d=8 = softmax denominator (same approx p in
// numerator and denominator -> self-consistent normalization).
__global__ __launch_bounds__(512, 4) void k_attn(float* __restrict__ ws) {
    const int h = blockIdx.y;
    const int q0 = blockIdx.x * 32;
    const int tid = threadIdx.x;
    const int w = tid >> 6;          // 0..7 t-chunk
    const int lane = tid & 63;
    const int col16 = lane & 15;
    const int quad = lane >> 4;
    const int col32 = lane & 31;
    const int half = lane >> 5;

    const char* base = (const char*)ws;
    const _Float16* Qt = (const _Float16*)(base + QT_B) + (size_t)h * 4096 * 8;
    const _Float16* Kt = (const _Float16*)(base + KT_B) + (size_t)h * 4096 * 8;
    const _Float16* Vb = (const _Float16*)(base + VB_B) + (size_t)h * 8 * 4096;

    // [w][32][40] halves = 8*32*40*2 = 20480 B; red aliases it after the loop
    __shared__ __align__(16) char smem[20480 + 14336];
    _Float16* Pw = (_Float16*)smem + (size_t)w * 1280;
    f4_t* red = (f4_t*)(smem + 20480);

    // Q B-frag (32x32x16): lane<32 holds Q[s=col32][d=0..7]; upper half zero
    H8 qf;
    qf.i[0] = qf.i[1] = qf.i[2] = qf.i[3] = 0;
    if (half == 0) qf.v = *(const int4*)(Qt + (size_t)(q0 + col32) * 8);

    // K A-frag: lane<32 holds K[t=col32][d=0..7]; upper half stays zero
    H8 kf;
    kf.i[0] = kf.i[1] = kf.i[2] = kf.i[3] = 0;
    // V A-frag (16x16x32): rows m=d: d<8 data (loaded per iter), d==8 ones, else 0
    H8 vf;
    {
        int c8 = (col16 == 8) ? 0x3C003C00 : 0;
        vf.i[0] = c8; vf.i[1] = c8; vf.i[2] = c8; vf.i[3] = c8;
    }

    const int tbase = w * 512;
    if (half == 0) kf.v = *(const int4*)(Kt + (size_t)(tbase + col32) * 8);

    f4_t acc0 = {0.f, 0.f, 0.f, 0.f};
    f4_t acc1 = {0.f, 0.f, 0.f, 0.f};
    f16_t zc = {0.f, 0.f, 0.f, 0.f, 0.f, 0.f, 0.f, 0.f,
                0.f, 0.f, 0.f, 0.f, 0.f, 0.f, 0.f, 0.f};

    for (int it = 0; it < 16; ++it) {
        const int tt = tbase + it * 32;
        // V for THIS iter: consumer (PV) is after exp+LDS round-trip -> slack
        if (col16 < 8)
            vf.v = *(const int4*)(Vb + (size_t)col16 * 4096 + tt + quad * 8);

        f16_t sc = __builtin_amdgcn_mfma_f32_32x32x16_f16(kf.h, qf.h, zc, 0, 0, 0);

        // prefetch next K tile (reads past-end junk at it=15 stay inside ws)
        H8 nk = kf;                      // keeps upper-half zeros
        if (half == 0)
            nk.v = *(const int4*)(Kt + (size_t)(tt + 32 + col32) * 8);

        // Schraudolph exp2 -> f16 bits, packed pairs; one b64 write per b
        #pragma unroll
        for (int b = 0; b < 4; ++b) {
            int i0 = EXP2_BITS(sc[4 * b + 0]);
            int i1 = EXP2_BITS(sc[4 * b + 1]);
            int i2 = EXP2_BITS(sc[4 * b + 2]);
            int i3 = EXP2_BITS(sc[4 * b + 3]);
            int2 wv = { i0 | (i1 << 16), i2 | (i3 << 16) };
            *(int2*)(Pw + col32 * 40 + 8 * b + 4 * half) = wv;
        }

        // B-frag reads: lane(quad,col16) takes P[s][t=quad*8..+7]
        H8 p0, p1;
        p0.v = *(const int4*)(Pw + col16 * 40 + quad * 8);
        p1.v = *(const int4*)(Pw + (col16 + 16) * 40 + quad * 8);

        acc0 = __builtin_amdgcn_mfma_f32_16x16x32_f16(vf.h, p0.h, acc0, 0, 0, 0);
        acc1 = __builtin_amdgcn_mfma_f32_16x16x32_f16(vf.h, p1.h, acc1, 0, 0, 0);

        kf = nk;
    }

    __syncthreads();   // all P reads done; safe to use the red region
    if (w > 0) {
        red[((w - 1) * 2 + 0) * 64 + lane] = acc0;
        red[((w - 1) * 2 + 1) * 64 + lane] = acc1;
    }
    __syncthreads();
    if (w == 0) {
        #pragma unroll
        for (int r = 0; r < 7; ++r) {
            acc0 += red[(r * 2 + 0) * 64 + lane];
            acc1 += red[(r * 2 + 1) * 64 + lane];
        }
        float inv0 = 1.0f / __shfl(acc0[0], 32 + col16, 64);  // row d=8 = denom
        float inv1 = 1.0f / __shfl(acc1[0], 32 + col16, 64);
        if (quad < 2) {
            float* att = ws + WS_ATT + (size_t)(h * 8 + quad * 4) * S + q0;
            #pragma unroll
            for (int r = 0; r < 4; ++r) {
                att[r * S + col16]      = acc0[r] * inv0;
                att[r * S + 16 + col16] = acc1[r] * inv1;
            }
        }
    }
}

// ---------------- Out projection + bias + residual ----------------
// grid (16, 64), block 256: s-tile 256 (1 s/thread), o-tile 1 -> 1024 blocks
__global__ __launch_bounds__(256) void k_out(const float* __restrict__ x,
                                             const float* __restrict__ outw,
                                             const float* __restrict__ outb,
                                             const float* __restrict__ ws,
                                             float* __restrict__ out) {
    __shared__ float lw[64];
    int tid = threadIdx.x;
    int o = blockIdx.y;
    int s = blockIdx.x * 256 + tid;
    if (tid < 64) lw[tid] = outw[o * 64 + tid];
    __syncthreads();

    float acc = outb[o];
    const float* att = ws + WS_ATT;
    for (int c = 0; c < 64; ++c)
        acc = fmaf(lw[c], att[c * S + s], acc);
    out[o * S + s] = acc + x[o * S + s];
}

extern "C" void kernel_launch(void* const* d_in, const int* in_sizes, int n_in,
                              void* d_out, int out_size, void* d_ws, size_t ws_size,
                              hipStream_t stream) {
    const float* x    = (const float*)d_in[0];
    const float* gnw  = (const float*)d_in[1];
    const float* gnb  = (const float*)d_in[2];
    const float* qkvw = (const float*)d_in[3];
    const float* outw = (const float*)d_in[4];
    const float* outb = (const float*)d_in[5];
    float* out = (float*)d_out;
    float* ws  = (float*)d_ws;

    hipLaunchKernelGGL(k_gnstat1, dim3(64), dim3(256), 0, stream, x, ws);
    hipLaunchKernelGGL(k_qkv, dim3(16, 48), dim3(256), 0, stream, x, qkvw, gnw, gnb, ws);
    hipLaunchKernelGGL(k_attn, dim3(128, 8), dim3(512), 0, stream, ws);
    hipLaunchKernelGGL(k_out, dim3(16, 64), dim3(256), 0, stream, x, outw, outb, ws, out);
}